// Round 3
// baseline (187.141 us; speedup 1.0000x reference)
//
#include <hip/hip_runtime.h>
#include <hip/hip_bf16.h>
#include <stdint.h>

// BatchHardTripletLoss: N=4096, D=512, C=128, margin=0.3
// hardest-pos = min gram (same label, j!=i), hardest-neg = max gram (diff label).
// Gram symmetric => upper-triangular 128x128 tiles (528 blocks).
//
// R3: decomposition across rounds: dur ~= 43.8us (harness ws-poison fill, fixed
// tax) + gram + ~17us (norm+final+gaps). gram ~28.7us vs ~1us MFMA floor =>
// latency-exposure at 2 waves/SIMD. Changes:
//  - gram: 512-thr blocks, 8 waves (2x4), wave-tile 64x32, ring-3 prefetch,
//    __launch_bounds__(512,4) => 4 waves/SIMD (2x latency hiding). setprio(1)
//    around MFMA cluster (free-running waves = the regime where it helps).
//  - tl_final fused into gram via done-counter; last block reduces with
//    agent-scope atomic loads (saves one launch + gap).
//  - norm: 4 rows/wave so swizzled stores are 64B-granular, not 16B scatter.
// Ebf layout (16B units): off16(row,kchunk) = (kchunk/4)*16384 + (row/16)*64
//   + (kchunk&3)*16 + (row&15)  -> MFMA fragment load = contiguous 1KB/wave.

#define NROW 4096
#define DIM  512
#define MARGIN 0.3f
#define BT 128
#define NTILE (NROW / BT)                 // 32
#define NPAIR (NTILE * (NTILE + 1) / 2)   // 528
#define POS_INIT 0xFFFFFFFFu
#define NEG_INIT 0u

typedef __attribute__((ext_vector_type(8))) __bf16 bf16x8;
typedef __attribute__((ext_vector_type(4))) float  f32x4;
typedef __attribute__((ext_vector_type(8))) unsigned short u16x8;

// monotone float<->uint: order-preserving for atomicMin/Max on unsigned.
// enc(finite f) never equals POS_INIT (needs NaN) nor NEG_INIT (needs -NaN),
// so the init sentinels double as "no positive/negative seen" flags.
__device__ __forceinline__ unsigned enc(float f) {
    unsigned u = __float_as_uint(f);
    return (u & 0x80000000u) ? ~u : (u | 0x80000000u);
}
__device__ __forceinline__ float dec(unsigned e) {
    return (e & 0x80000000u) ? __uint_as_float(e & 0x7fffffffu)
                             : __uint_as_float(~e);
}

__device__ __forceinline__ unsigned short f2bf(float f) {
    __hip_bfloat16 h = __float2bfloat16(f);
    return *reinterpret_cast<unsigned short*>(&h);
}

// ---- kernel 1: L2-normalize rows -> bf16 swizzled layout, + init arrays ----
// 256 blocks x 256 thr; block b normalizes rtile b (16 rows). Wave w: rows
// w*4..w*4+3 of the tile; lane = (r2=lane>>4, kc=lane&15); lane owns the row's
// elements [kc*32, kc*32+32) = ktile kc, c_in 0..3 -> 4 stores, 64B-granular.
__global__ void tl_norm(const float* __restrict__ E,
                        __hip_bfloat16* __restrict__ Ebf,
                        unsigned* __restrict__ posArr,
                        unsigned* __restrict__ negArr,
                        unsigned* __restrict__ doneCnt) {
    if (blockIdx.x < 16) {
        int t = blockIdx.x * 256 + threadIdx.x;   // covers 4096
        posArr[t] = POS_INIT;
        negArr[t] = NEG_INIT;
    }
    if (blockIdx.x == 16 && threadIdx.x == 0) *doneCnt = 0;

    const int wave  = threadIdx.x >> 6;
    const int lane  = threadIdx.x & 63;
    const int r2    = lane >> 4;        // 0..3
    const int kc    = lane & 15;        // k-chunk-of-32
    const int rtile = blockIdx.x;       // 0..255
    const int r_in  = wave * 4 + r2;    // 0..15
    const int row   = rtile * 16 + r_in;

    const float4* src = (const float4*)(E + (size_t)row * DIM) + kc * 8;
    float4 v[8];
    #pragma unroll
    for (int i = 0; i < 8; i++) v[i] = src[i];

    float ss = 0.0f;
    #pragma unroll
    for (int i = 0; i < 8; i++)
        ss += v[i].x*v[i].x + v[i].y*v[i].y + v[i].z*v[i].z + v[i].w*v[i].w;
    // reduce across the 16 lanes sharing this row (same lane>>4 group)
    #pragma unroll
    for (int m = 1; m < 16; m <<= 1) ss += __shfl_xor(ss, m);
    const float inv = 1.0f / fmaxf(sqrtf(ss), 1e-12f);

    u16x8* dst = (u16x8*)Ebf + (size_t)kc * 16384 + (size_t)rtile * 64 + r_in;
    #pragma unroll
    for (int c = 0; c < 4; c++) {
        const float4 lo = v[2*c], hi = v[2*c + 1];
        u16x8 o;
        o[0] = f2bf(lo.x * inv); o[1] = f2bf(lo.y * inv);
        o[2] = f2bf(lo.z * inv); o[3] = f2bf(lo.w * inv);
        o[4] = f2bf(hi.x * inv); o[5] = f2bf(hi.y * inv);
        o[6] = f2bf(hi.z * inv); o[7] = f2bf(hi.w * inv);
        dst[c * 16] = o;   // 4 lanes (r2=0..3) -> 64B contiguous per group
    }
}

// ---- kernel 2: upper-triangular bf16 MFMA Gram + fused final reduction ----
// 528 blocks x 512 thr (8 waves, 2x4 over 128x128; wave-tile 64x32).
// Direct-from-L2 swizzled fragment loads, ring-3 prefetch, zero barriers in
// the K-loop. Last block to finish computes the loss (done-counter).
__global__ void __launch_bounds__(512, 4)
tl_gram(const __hip_bfloat16* __restrict__ Ebf,
        const int* __restrict__ labels,
        unsigned* __restrict__ posArr,
        unsigned* __restrict__ negArr,
        unsigned* __restrict__ doneCnt,
        float* __restrict__ out) {
    __shared__ int rowLab[BT];
    __shared__ int colLab[BT];

    // bijective XCD swizzle: 528 = 8 * 66; consecutive t (same bi -> shared
    // A-panel) land on the same XCD's L2.
    int bid = blockIdx.x;
    int t = (bid & 7) * (NPAIR / 8) + (bid >> 3);

    // triangular decode: t -> (bi, bj), bi <= bj
    int bi = 0, rowlen = NTILE;
    while (t >= rowlen) { t -= rowlen; rowlen--; bi++; }
    const int bj = bi + t;

    const int tid  = threadIdx.x;
    const int wave = tid >> 6;
    const int lane = tid & 63;
    const int quad = lane >> 4;
    const int l16  = lane & 15;
    const int wr   = wave >> 2;   // 0..1: rows wr*64..+63
    const int wc   = wave & 3;    // 0..3: cols wc*32..+31
    const int tileI = bi * BT;
    const int tileJ = bj * BT;
    const bool diag = (bi == bj);

    if (tid < BT)            rowLab[tid] = labels[tileI + tid];
    else if (tid < 2 * BT)   colLab[tid - BT] = labels[tileJ + (tid - BT)];
    __syncthreads();   // only block-wide sync before the epilogue

    // swizzled fragment base: frag(rowbase,kk) at 16B-unit offset
    //   kk*16384 + (rowbase/16)*64 + lane   (lane-contiguous 1KB)
    const bf16x8* Ev = (const bf16x8*)Ebf;
    const bf16x8* Ea = Ev + ((tileI + wr * 64) >> 4) * 64 + lane;
    const bf16x8* Eb = Ev + ((tileJ + wc * 32) >> 4) * 64 + lane;

    f32x4 acc[4][2] = {};
    bf16x8 a[3][4], b[3][2];   // ring slot x frag, all indices compile-time

    #pragma unroll
    for (int p = 0; p < 2; ++p) {
        #pragma unroll
        for (int mi = 0; mi < 4; mi++) a[p][mi] = Ea[p * 16384 + mi * 64];
        #pragma unroll
        for (int ni = 0; ni < 2; ni++) b[p][ni] = Eb[p * 16384 + ni * 64];
    }
    #pragma unroll
    for (int kk = 0; kk < 16; ++kk) {      // 16 K-steps of 32
        const int cur = kk % 3;
        if (kk + 2 < 16) {
            const int nx = (kk + 2) % 3;
            #pragma unroll
            for (int mi = 0; mi < 4; mi++)
                a[nx][mi] = Ea[(kk + 2) * 16384 + mi * 64];
            #pragma unroll
            for (int ni = 0; ni < 2; ni++)
                b[nx][ni] = Eb[(kk + 2) * 16384 + ni * 64];
        }
        __builtin_amdgcn_s_setprio(1);
        #pragma unroll
        for (int mi = 0; mi < 4; mi++)
            #pragma unroll
            for (int ni = 0; ni < 2; ni++)
                acc[mi][ni] = __builtin_amdgcn_mfma_f32_16x16x32_bf16(
                    a[cur][mi], b[cur][ni], acc[mi][ni], 0, 0, 0);
        __builtin_amdgcn_s_setprio(0);
    }

    // C/D layout: col = wc*32+ni*16+l16 (lane), row = wr*64+mi*16+quad*4+reg
    int rl[16], cl[2], clocv[2];
    #pragma unroll
    for (int mi = 0; mi < 4; mi++)
        #pragma unroll
        for (int reg = 0; reg < 4; reg++)
            rl[mi * 4 + reg] = rowLab[wr * 64 + mi * 16 + quad * 4 + reg];
    #pragma unroll
    for (int ni = 0; ni < 2; ni++) {
        clocv[ni] = wc * 32 + ni * 16 + l16;
        cl[ni] = colLab[clocv[ni]];
    }

    // ---- row pass: reduce over this wave's 32 columns, rows of tileI ----
    #pragma unroll
    for (int mi = 0; mi < 4; mi++) {
        #pragma unroll
        for (int reg = 0; reg < 4; reg++) {
            const int rloc = wr * 64 + mi * 16 + quad * 4 + reg;
            const int lr   = rl[mi * 4 + reg];
            const int gi   = tileI + rloc;
            float pmin =  INFINITY;
            float nmax = -INFINITY;
            #pragma unroll
            for (int ni = 0; ni < 2; ni++) {
                const int gj  = tileJ + clocv[ni];
                const float g = acc[mi][ni][reg];
                const bool same = (lr == cl[ni]);
                if (same && gi != gj) pmin = fminf(pmin, g);
                if (!same)            nmax = fmaxf(nmax, g);
            }
            #pragma unroll
            for (int m = 1; m < 16; m <<= 1) {
                pmin = fminf(pmin, __shfl_xor(pmin, m));
                nmax = fmaxf(nmax, __shfl_xor(nmax, m));
            }
            if (l16 == 0) {
                if (pmin <  INFINITY) atomicMin(&posArr[gi], enc(pmin));
                if (nmax > -INFINITY) atomicMax(&negArr[gi], enc(nmax));
            }
        }
    }

    // ---- col pass (off-diag only): reduce over this wave's 64 rows ----
    if (!diag) {
        #pragma unroll
        for (int ni = 0; ni < 2; ni++) {
            const int lc = cl[ni];
            const int gj = tileJ + clocv[ni];
            float pmin =  INFINITY;
            float nmax = -INFINITY;
            #pragma unroll
            for (int mi = 0; mi < 4; mi++) {
                #pragma unroll
                for (int reg = 0; reg < 4; reg++) {
                    const float g = acc[mi][ni][reg];
                    const bool same = (rl[mi * 4 + reg] == lc);
                    if (same) pmin = fminf(pmin, g);
                    else      nmax = fmaxf(nmax, g);
                }
            }
            pmin = fminf(pmin, __shfl_xor(pmin, 16));
            pmin = fminf(pmin, __shfl_xor(pmin, 32));
            nmax = fmaxf(nmax, __shfl_xor(nmax, 16));
            nmax = fmaxf(nmax, __shfl_xor(nmax, 32));
            if (quad == 0) {
                if (pmin <  INFINITY) atomicMin(&posArr[gj], enc(pmin));
                if (nmax > -INFINITY) atomicMax(&negArr[gj], enc(nmax));
            }
        }
    }

    // ---- fused final: last block to finish reduces the loss ----
    __shared__ unsigned sOld;
    __threadfence();     // release this block's atomics
    __syncthreads();
    if (tid == 0) sOld = atomicAdd(doneCnt, 1u);
    __syncthreads();
    if (sOld == NPAIR - 1) {
        __threadfence();  // acquire
        float sum = 0.0f;
        int   cnt = 0;
        for (int i = tid; i < NROW; i += 512) {
            const unsigned pe = __hip_atomic_load(&posArr[i], __ATOMIC_RELAXED,
                                                  __HIP_MEMORY_SCOPE_AGENT);
            const unsigned ne = __hip_atomic_load(&negArr[i], __ATOMIC_RELAXED,
                                                  __HIP_MEMORY_SCOPE_AGENT);
            const bool valid = (pe != POS_INIT) && (ne != NEG_INIT);
            const float dap = sqrtf(fmaxf(2.0f - 2.0f * dec(pe), 0.0f));
            const float dan = sqrtf(fmaxf(2.0f - 2.0f * dec(ne), 0.0f));
            const float per = fmaxf(dap - dan + MARGIN, 0.0f);
            if (valid) { sum += per; cnt += 1; }
        }
        #pragma unroll
        for (int m = 32; m >= 1; m >>= 1) {
            sum += __shfl_xor(sum, m);
            cnt += __shfl_xor(cnt, m);
        }
        __shared__ float ssum[8];
        __shared__ int   scnt[8];
        if (lane == 0) { ssum[wave] = sum; scnt[wave] = cnt; }
        __syncthreads();
        if (tid == 0) {
            float s = 0.0f; int c = 0;
            #pragma unroll
            for (int w = 0; w < 8; w++) { s += ssum[w]; c += scnt[w]; }
            out[0] = (c > 0) ? (s / (float)c) : 0.0f;
        }
    }
}

extern "C" void kernel_launch(void* const* d_in, const int* in_sizes, int n_in,
                              void* d_out, int out_size, void* d_ws, size_t ws_size,
                              hipStream_t stream) {
    const float* E      = (const float*)d_in[0];
    const int*   labels = (const int*)d_in[1];
    float*       out    = (float*)d_out;

    char* ws = (char*)d_ws;
    __hip_bfloat16* Ebf   = (__hip_bfloat16*)ws;                       // 4 MB
    unsigned* posArr      = (unsigned*)(ws + (size_t)NROW * DIM * 2);  // 16 KB
    unsigned* negArr      = posArr + NROW;                             // 16 KB
    unsigned* doneCnt     = negArr + NROW;                             // 4 B

    tl_norm<<<NROW / 16, 256, 0, stream>>>(E, Ebf, posArr, negArr, doneCnt);
    tl_gram<<<NPAIR, 512, 0, stream>>>(Ebf, labels, posArr, negArr, doneCnt, out);
}

// Round 5
// 101.895 us; speedup vs baseline: 1.8366x; 1.8366x over previous
//
#include <hip/hip_runtime.h>
#include <hip/hip_bf16.h>
#include <stdint.h>

// BatchHardTripletLoss: N=4096, D=512, C=128, margin=0.3
// hardest-pos = min gram (same label, j!=i), hardest-neg = max gram (diff label).
// Gram symmetric => upper-triangular 128x128 tiles; split into two 128x64
// column-half blocks (1056 blocks) to raise resident waves/SIMD (2 -> 3).
//
// R5 = R4 resubmitted verbatim (R4 bench died to infra: "container failed
// twice", no counters). R3 post-mortem still applies: per-block __threadfence
// (cross-XCD L2 writeback x528) and the (512,4) VGPR cap caused the 4.5x
// regression; both remain removed. Structure = R2 3-kernel pipeline with ONE
// change vs R2: half-tile blocks for occupancy, launch_bounds(256,3).
//
// Ebf swizzled layout (16B units): off16(row, kchunk) = (kchunk/4)*16384
//   + (row/16)*64 + (kchunk&3)*16 + (row&15)
// => MFMA fragment load (16 rows x 32 k) = one contiguous 1KB wave load.

#define NROW 4096
#define DIM  512
#define MARGIN 0.3f
#define BT 128
#define NTILE (NROW / BT)                 // 32
#define NPAIR (NTILE * (NTILE + 1) / 2)   // 528
#define NBLK  (NPAIR * 2)                 // 1056 half-tile blocks
#define POS_INIT 0xFFFFFFFFu
#define NEG_INIT 0u

typedef __attribute__((ext_vector_type(8))) __bf16 bf16x8;
typedef __attribute__((ext_vector_type(4))) float  f32x4;
typedef __attribute__((ext_vector_type(8))) unsigned short u16x8;

// monotone float<->uint: order-preserving for atomicMin/Max on unsigned.
// enc(finite f) never equals POS_INIT (needs NaN) nor NEG_INIT (needs -NaN),
// so the init sentinels double as "no positive/negative seen" flags.
__device__ __forceinline__ unsigned enc(float f) {
    unsigned u = __float_as_uint(f);
    return (u & 0x80000000u) ? ~u : (u | 0x80000000u);
}
__device__ __forceinline__ float dec(unsigned e) {
    return (e & 0x80000000u) ? __uint_as_float(e & 0x7fffffffu)
                             : __uint_as_float(~e);
}

__device__ __forceinline__ unsigned short f2bf(float f) {
    __hip_bfloat16 h = __float2bfloat16(f);
    return *reinterpret_cast<unsigned short*>(&h);
}

// ---- kernel 1: L2-normalize rows -> bf16 swizzled layout, + init arrays ----
// 256 blocks x 256 thr; block b = rtile b (16 rows). Wave w: rows w*4..+3;
// lane = (r2=lane>>4, kc=lane&15); lane owns k in [kc*32, kc*32+32) -> ktile
// kc, c_in 0..3 -> 4 stores, 64B-granular across the 4-lane r2 groups.
__global__ void tl_norm(const float* __restrict__ E,
                        __hip_bfloat16* __restrict__ Ebf,
                        unsigned* __restrict__ posArr,
                        unsigned* __restrict__ negArr) {
    if (blockIdx.x < 16) {
        int t = blockIdx.x * 256 + threadIdx.x;   // covers 4096
        posArr[t] = POS_INIT;
        negArr[t] = NEG_INIT;
    }
    const int wave  = threadIdx.x >> 6;
    const int lane  = threadIdx.x & 63;
    const int r2    = lane >> 4;        // 0..3
    const int kc    = lane & 15;        // k-chunk-of-32
    const int rtile = blockIdx.x;       // 0..255
    const int r_in  = wave * 4 + r2;    // 0..15
    const int row   = rtile * 16 + r_in;

    const float4* src = (const float4*)(E + (size_t)row * DIM) + kc * 8;
    float4 v[8];
    #pragma unroll
    for (int i = 0; i < 8; i++) v[i] = src[i];

    float ss = 0.0f;
    #pragma unroll
    for (int i = 0; i < 8; i++)
        ss += v[i].x*v[i].x + v[i].y*v[i].y + v[i].z*v[i].z + v[i].w*v[i].w;
    // reduce across the 16 lanes sharing this row (r2 group preserved, m<16)
    #pragma unroll
    for (int m = 1; m < 16; m <<= 1) ss += __shfl_xor(ss, m);
    const float inv = 1.0f / fmaxf(sqrtf(ss), 1e-12f);

    u16x8* dst = (u16x8*)Ebf + (size_t)kc * 16384 + (size_t)rtile * 64 + r_in;
    #pragma unroll
    for (int c = 0; c < 4; c++) {
        const float4 lo = v[2*c], hi = v[2*c + 1];
        u16x8 o;
        o[0] = f2bf(lo.x * inv); o[1] = f2bf(lo.y * inv);
        o[2] = f2bf(lo.z * inv); o[3] = f2bf(lo.w * inv);
        o[4] = f2bf(hi.x * inv); o[5] = f2bf(hi.y * inv);
        o[6] = f2bf(hi.z * inv); o[7] = f2bf(hi.w * inv);
        dst[c * 16] = o;
    }
}

// ---- kernel 2: upper-tri bf16 MFMA Gram, 128x64 half-tile blocks ----
// 1056 blocks x 256 thr (4 waves, 2x2 over 128 rows x 64 cols; wave 64x32).
// Direct-from-L2 swizzled fragment loads, ring-4 prefetch, zero barriers in
// the K-loop. Row pass + (off-diag) col pass feed sentinel atomics.
__global__ void __launch_bounds__(256, 3)
tl_gram(const __hip_bfloat16* __restrict__ Ebf,
        const int* __restrict__ labels,
        unsigned* __restrict__ posArr,
        unsigned* __restrict__ negArr) {
    __shared__ int rowLab[BT];
    __shared__ int colLab[64];

    // bijective XCD swizzle: 1056 = 8 * 132; consecutive swz ids (same bi ->
    // shared A panel) land on the same XCD's L2.
    const int bid = blockIdx.x;
    const int swz = (bid & 7) * (NBLK / 8) + (bid >> 3);
    int t = swz >> 1;                 // tile pair 0..527
    const int h = swz & 1;            // column half 0..1

    // triangular decode: t -> (bi, bj), bi <= bj
    int bi = 0, rowlen = NTILE;
    while (t >= rowlen) { t -= rowlen; rowlen--; bi++; }
    const int bj = bi + t;

    const int tid  = threadIdx.x;
    const int wave = tid >> 6;
    const int lane = tid & 63;
    const int quad = lane >> 4;
    const int l16  = lane & 15;
    const int wr   = wave >> 1;   // 0..1: rows wr*64..+63
    const int wc   = wave & 1;    // 0..1: cols wc*32..+31 (within the half)
    const int tileI = bi * BT;
    const int tileJ = bj * BT + h * 64;   // this block's 64-col band
    const bool diag = (bi == bj);

    if (tid < BT)            rowLab[tid] = labels[tileI + tid];
    else if (tid < BT + 64)  colLab[tid - BT] = labels[tileJ + (tid - BT)];
    __syncthreads();   // the only block-wide sync

    // swizzled fragment base: frag(rowbase,kk) at 16B-unit offset
    //   kk*16384 + (rowbase/16)*64 + lane   (lane-contiguous 1KB)
    const bf16x8* Ev = (const bf16x8*)Ebf;
    const bf16x8* Ea = Ev + ((tileI + wr * 64) >> 4) * 64 + lane;
    const bf16x8* Eb = Ev + ((tileJ + wc * 32) >> 4) * 64 + lane;

    f32x4 acc[4][2] = {};
    bf16x8 a[4][4], b[4][2];   // ring slot x frag, all indices compile-time

    #pragma unroll
    for (int p = 0; p < 3; ++p) {
        #pragma unroll
        for (int mi = 0; mi < 4; mi++) a[p][mi] = Ea[p * 16384 + mi * 64];
        #pragma unroll
        for (int ni = 0; ni < 2; ni++) b[p][ni] = Eb[p * 16384 + ni * 64];
    }
    #pragma unroll
    for (int kk = 0; kk < 16; ++kk) {      // 16 K-steps of 32
        const int cur = kk & 3;
        if (kk + 3 < 16) {
            const int nx = (kk + 3) & 3;
            #pragma unroll
            for (int mi = 0; mi < 4; mi++)
                a[nx][mi] = Ea[(kk + 3) * 16384 + mi * 64];
            #pragma unroll
            for (int ni = 0; ni < 2; ni++)
                b[nx][ni] = Eb[(kk + 3) * 16384 + ni * 64];
        }
        #pragma unroll
        for (int mi = 0; mi < 4; mi++)
            #pragma unroll
            for (int ni = 0; ni < 2; ni++)
                acc[mi][ni] = __builtin_amdgcn_mfma_f32_16x16x32_bf16(
                    a[cur][mi], b[cur][ni], acc[mi][ni], 0, 0, 0);
    }

    // C/D layout: col = wc*32+ni*16+l16 (lane), row = wr*64+mi*16+quad*4+reg
    int rl[16], cl[2], clocv[2];
    #pragma unroll
    for (int mi = 0; mi < 4; mi++)
        #pragma unroll
        for (int reg = 0; reg < 4; reg++)
            rl[mi * 4 + reg] = rowLab[wr * 64 + mi * 16 + quad * 4 + reg];
    #pragma unroll
    for (int ni = 0; ni < 2; ni++) {
        clocv[ni] = wc * 32 + ni * 16 + l16;
        cl[ni] = colLab[clocv[ni]];
    }

    // ---- row pass: reduce over this wave's 32 cols, rows of tileI ----
    #pragma unroll
    for (int mi = 0; mi < 4; mi++) {
        #pragma unroll
        for (int reg = 0; reg < 4; reg++) {
            const int rloc = wr * 64 + mi * 16 + quad * 4 + reg;
            const int lr   = rl[mi * 4 + reg];
            const int gi   = tileI + rloc;
            float pmin =  INFINITY;
            float nmax = -INFINITY;
            #pragma unroll
            for (int ni = 0; ni < 2; ni++) {
                const int gj  = tileJ + clocv[ni];
                const float g = acc[mi][ni][reg];
                const bool same = (lr == cl[ni]);
                if (same && gi != gj) pmin = fminf(pmin, g);
                if (!same)            nmax = fmaxf(nmax, g);
            }
            #pragma unroll
            for (int m = 1; m < 16; m <<= 1) {
                pmin = fminf(pmin, __shfl_xor(pmin, m));
                nmax = fmaxf(nmax, __shfl_xor(nmax, m));
            }
            if (l16 == 0) {
                if (pmin <  INFINITY) atomicMin(&posArr[gi], enc(pmin));
                if (nmax > -INFINITY) atomicMax(&negArr[gi], enc(nmax));
            }
        }
    }

    // ---- col pass (off-diag only): reduce over this wave's 64 rows ----
    // diag tiles: every unordered pair appears in some half-block's row pass.
    if (!diag) {
        #pragma unroll
        for (int ni = 0; ni < 2; ni++) {
            const int lc = cl[ni];
            const int gj = tileJ + clocv[ni];
            float pmin =  INFINITY;
            float nmax = -INFINITY;
            #pragma unroll
            for (int mi = 0; mi < 4; mi++) {
                #pragma unroll
                for (int reg = 0; reg < 4; reg++) {
                    const float g = acc[mi][ni][reg];
                    const bool same = (rl[mi * 4 + reg] == lc);
                    if (same) pmin = fminf(pmin, g);
                    else      nmax = fmaxf(nmax, g);
                }
            }
            pmin = fminf(pmin, __shfl_xor(pmin, 16));
            pmin = fminf(pmin, __shfl_xor(pmin, 32));
            nmax = fmaxf(nmax, __shfl_xor(nmax, 16));
            nmax = fmaxf(nmax, __shfl_xor(nmax, 32));
            if (quad == 0) {
                if (pmin <  INFINITY) atomicMin(&posArr[gj], enc(pmin));
                if (nmax > -INFINITY) atomicMax(&negArr[gj], enc(nmax));
            }
        }
    }
}

// ---- kernel 3: per-row loss + mean over valid rows ----
__global__ void tl_final(const unsigned* __restrict__ posArr,
                         const unsigned* __restrict__ negArr,
                         float* __restrict__ out) {
    const int tid = threadIdx.x; // 1024 threads, 4 rows each, single pass
    uint4 pe4 = ((const uint4*)posArr)[tid];
    uint4 ne4 = ((const uint4*)negArr)[tid];
    unsigned pes[4] = {pe4.x, pe4.y, pe4.z, pe4.w};
    unsigned nes[4] = {ne4.x, ne4.y, ne4.z, ne4.w};
    float sum = 0.0f;
    int   count = 0;
    #pragma unroll
    for (int j = 0; j < 4; j++) {
        const bool valid = (pes[j] != POS_INIT) && (nes[j] != NEG_INIT);
        const float dap = sqrtf(fmaxf(2.0f - 2.0f * dec(pes[j]), 0.0f));
        const float dan = sqrtf(fmaxf(2.0f - 2.0f * dec(nes[j]), 0.0f));
        const float per = fmaxf(dap - dan + MARGIN, 0.0f);
        if (valid) { sum += per; count += 1; }
    }
    #pragma unroll
    for (int m = 32; m >= 1; m >>= 1) {
        sum   += __shfl_xor(sum, m);
        count += __shfl_xor(count, m);
    }
    __shared__ float ssum[16];
    __shared__ int   scnt[16];
    const int wave = tid >> 6, lane = tid & 63;
    if (lane == 0) { ssum[wave] = sum; scnt[wave] = count; }
    __syncthreads();
    if (tid == 0) {
        float s = 0.0f; int c = 0;
        #pragma unroll
        for (int w = 0; w < 16; w++) { s += ssum[w]; c += scnt[w]; }
        out[0] = (c > 0) ? (s / (float)c) : 0.0f;
    }
}

extern "C" void kernel_launch(void* const* d_in, const int* in_sizes, int n_in,
                              void* d_out, int out_size, void* d_ws, size_t ws_size,
                              hipStream_t stream) {
    const float* E      = (const float*)d_in[0];
    const int*   labels = (const int*)d_in[1];
    float*       out    = (float*)d_out;

    char* ws = (char*)d_ws;
    __hip_bfloat16* Ebf   = (__hip_bfloat16*)ws;                       // 4 MB
    unsigned* posArr      = (unsigned*)(ws + (size_t)NROW * DIM * 2);  // 16 KB
    unsigned* negArr      = posArr + NROW;                             // 16 KB

    tl_norm<<<NROW / 16, 256, 0, stream>>>(E, Ebf, posArr, negArr);
    tl_gram<<<NBLK, 256, 0, stream>>>(Ebf, labels, posArr, negArr);
    tl_final<<<1, 1024, 0, stream>>>(posArr, negArr, out);
}

// Round 6
// 92.599 us; speedup vs baseline: 2.0210x; 1.1004x over previous
//
#include <hip/hip_runtime.h>
#include <hip/hip_bf16.h>
#include <stdint.h>

// BatchHardTripletLoss: N=4096, D=512, C=128, margin=0.3
// hardest-pos = min gram (same label, j!=i), hardest-neg = max gram (diff label).
// Gram symmetric => upper-triangular 128x128 tiles (528 blocks).
//
// R6 = R2 structure (best measured gram, ~28.7us) + ONE mechanism change:
// sched_barrier(0) between the prefetch-load cluster and the MFMA cluster in
// every K-iteration. Evidence: rocprof VGPR_Count=64 on the R2/R3 codegen =>
// the compiler SANK the ring-4 prefetch loads to just before their uses (the
// ring never existed in the emitted code; every K-step ate full L2/L3 latency
// serially). sched_barrier(0) pins issue order: 24 loads stay in flight, the
// compiler's exact vmcnt(N) waits engage 3 steps later. launch_bounds(256,2)
// raises the VGPR cap so the ~200-reg live set fits at R2's 2 blocks/CU.
// R5's half-tile experiment (1056 blocks) REGRESSED (41us: more block
// generations x same per-block latency chain) and is reverted.
//
// Ebf swizzled layout (16B units): off16(row, kchunk) = (kchunk/4)*16384
//   + (row/16)*64 + (kchunk&3)*16 + (row&15)
// => MFMA fragment load (16 rows x 32 k) = one contiguous 1KB wave load.

#define NROW 4096
#define DIM  512
#define MARGIN 0.3f
#define BT 128
#define NTILE (NROW / BT)                 // 32
#define NPAIR (NTILE * (NTILE + 1) / 2)   // 528
#define POS_INIT 0xFFFFFFFFu
#define NEG_INIT 0u

typedef __attribute__((ext_vector_type(8))) __bf16 bf16x8;
typedef __attribute__((ext_vector_type(4))) float  f32x4;
typedef __attribute__((ext_vector_type(8))) unsigned short u16x8;

// monotone float<->uint: order-preserving for atomicMin/Max on unsigned.
// enc(finite f) never equals POS_INIT (needs NaN) nor NEG_INIT (needs -NaN),
// so the init sentinels double as "no positive/negative seen" flags.
__device__ __forceinline__ unsigned enc(float f) {
    unsigned u = __float_as_uint(f);
    return (u & 0x80000000u) ? ~u : (u | 0x80000000u);
}
__device__ __forceinline__ float dec(unsigned e) {
    return (e & 0x80000000u) ? __uint_as_float(e & 0x7fffffffu)
                             : __uint_as_float(~e);
}

__device__ __forceinline__ unsigned short f2bf(float f) {
    __hip_bfloat16 h = __float2bfloat16(f);
    return *reinterpret_cast<unsigned short*>(&h);
}

// ---- kernel 1: L2-normalize rows -> bf16 swizzled layout, + init arrays ----
// 256 blocks x 256 thr; block b = rtile b (16 rows). Wave w: rows w*4..+3;
// lane = (r2=lane>>4, kc=lane&15); lane owns k in [kc*32, kc*32+32) -> ktile
// kc, c_in 0..3 -> 4 stores, 64B-granular across the 4-lane r2 groups.
__global__ void tl_norm(const float* __restrict__ E,
                        __hip_bfloat16* __restrict__ Ebf,
                        unsigned* __restrict__ posArr,
                        unsigned* __restrict__ negArr) {
    if (blockIdx.x < 16) {
        int t = blockIdx.x * 256 + threadIdx.x;   // covers 4096
        posArr[t] = POS_INIT;
        negArr[t] = NEG_INIT;
    }
    const int wave  = threadIdx.x >> 6;
    const int lane  = threadIdx.x & 63;
    const int r2    = lane >> 4;        // 0..3
    const int kc    = lane & 15;        // k-chunk-of-32
    const int rtile = blockIdx.x;       // 0..255
    const int r_in  = wave * 4 + r2;    // 0..15
    const int row   = rtile * 16 + r_in;

    const float4* src = (const float4*)(E + (size_t)row * DIM) + kc * 8;
    float4 v[8];
    #pragma unroll
    for (int i = 0; i < 8; i++) v[i] = src[i];

    float ss = 0.0f;
    #pragma unroll
    for (int i = 0; i < 8; i++)
        ss += v[i].x*v[i].x + v[i].y*v[i].y + v[i].z*v[i].z + v[i].w*v[i].w;
    // reduce across the 16 lanes sharing this row (r2 group preserved, m<16)
    #pragma unroll
    for (int m = 1; m < 16; m <<= 1) ss += __shfl_xor(ss, m);
    const float inv = 1.0f / fmaxf(sqrtf(ss), 1e-12f);

    u16x8* dst = (u16x8*)Ebf + (size_t)kc * 16384 + (size_t)rtile * 64 + r_in;
    #pragma unroll
    for (int c = 0; c < 4; c++) {
        const float4 lo = v[2*c], hi = v[2*c + 1];
        u16x8 o;
        o[0] = f2bf(lo.x * inv); o[1] = f2bf(lo.y * inv);
        o[2] = f2bf(lo.z * inv); o[3] = f2bf(lo.w * inv);
        o[4] = f2bf(hi.x * inv); o[5] = f2bf(hi.y * inv);
        o[6] = f2bf(hi.z * inv); o[7] = f2bf(hi.w * inv);
        dst[c * 16] = o;
    }
}

// ---- kernel 2: upper-tri bf16 MFMA Gram, 128x128 tiles, forced ring-4 ----
// 528 blocks x 256 thr (4 waves, 2x2; wave-tile 64x64, 16 MFMA/K-step).
// Direct-from-L2 swizzled fragment loads; sched_barrier(0) pins the
// load-then-MFMA issue order so the ring-4 prefetch actually materializes.
__global__ void __launch_bounds__(256, 2)
tl_gram(const __hip_bfloat16* __restrict__ Ebf,
        const int* __restrict__ labels,
        unsigned* __restrict__ posArr,
        unsigned* __restrict__ negArr) {
    __shared__ int rowLab[BT];
    __shared__ int colLab[BT];

    // bijective XCD swizzle: 528 = 8 * 66; consecutive swz ids (same bi ->
    // shared A panel) land on the same XCD's L2.
    const int bid = blockIdx.x;
    int t = (bid & 7) * (NPAIR / 8) + (bid >> 3);

    // triangular decode: t -> (bi, bj), bi <= bj
    int bi = 0, rowlen = NTILE;
    while (t >= rowlen) { t -= rowlen; rowlen--; bi++; }
    const int bj = bi + t;

    const int tid  = threadIdx.x;
    const int wave = tid >> 6;
    const int lane = tid & 63;
    const int quad = lane >> 4;
    const int l16  = lane & 15;
    const int wr   = wave >> 1;   // 0..1: rows wr*64..+63
    const int wc   = wave & 1;    // 0..1: cols wc*64..+63
    const int tileI = bi * BT;
    const int tileJ = bj * BT;
    const bool diag = (bi == bj);

    if (tid < BT) rowLab[tid] = labels[tileI + tid];
    else          colLab[tid - BT] = labels[tileJ + (tid - BT)];
    __syncthreads();   // the only block-wide sync

    // swizzled fragment base: frag(rowbase,kk) at 16B-unit offset
    //   kk*16384 + (rowbase/16)*64 + lane   (lane-contiguous 1KB)
    const bf16x8* Ev = (const bf16x8*)Ebf;
    const bf16x8* Ea = Ev + ((tileI + wr * 64) >> 4) * 64 + lane;
    const bf16x8* Eb = Ev + ((tileJ + wc * 64) >> 4) * 64 + lane;

    f32x4 acc[4][4] = {};
    bf16x8 a[4][4], b[4][4];   // ring slot x frag, all indices compile-time

    #pragma unroll
    for (int p = 0; p < 3; ++p) {
        #pragma unroll
        for (int i = 0; i < 4; i++) {
            a[p][i] = Ea[p * 16384 + i * 64];
            b[p][i] = Eb[p * 16384 + i * 64];
        }
    }
    __builtin_amdgcn_sched_barrier(0);   // prologue loads issued before loop

    #pragma unroll
    for (int kk = 0; kk < 16; ++kk) {      // 16 K-steps of 32
        const int cur = kk & 3;
        if (kk + 3 < 16) {
            const int nx = (kk + 3) & 3;
            #pragma unroll
            for (int i = 0; i < 4; i++) {
                a[nx][i] = Ea[(kk + 3) * 16384 + i * 64];
                b[nx][i] = Eb[(kk + 3) * 16384 + i * 64];
            }
        }
        // Pin issue order: next-step loads BEFORE this step's MFMAs, so the
        // ring stays 3 steps deep in flight (compiler otherwise sinks the
        // loads to their uses — observed VGPR_Count=64, i.e. no ring at all).
        __builtin_amdgcn_sched_barrier(0);
        #pragma unroll
        for (int mi = 0; mi < 4; mi++)
            #pragma unroll
            for (int ni = 0; ni < 4; ni++)
                acc[mi][ni] = __builtin_amdgcn_mfma_f32_16x16x32_bf16(
                    a[cur][mi], b[cur][ni], acc[mi][ni], 0, 0, 0);
        __builtin_amdgcn_sched_barrier(0);
    }

    // C/D layout: col = wc*64+ni*16+l16 (lane), row = wr*64+mi*16+quad*4+reg
    int rl[16], cl[4], clocv[4];
    #pragma unroll
    for (int mi = 0; mi < 4; mi++)
        #pragma unroll
        for (int reg = 0; reg < 4; reg++)
            rl[mi * 4 + reg] = rowLab[wr * 64 + mi * 16 + quad * 4 + reg];
    #pragma unroll
    for (int ni = 0; ni < 4; ni++) {
        clocv[ni] = wc * 64 + ni * 16 + l16;
        cl[ni] = colLab[clocv[ni]];
    }

    // ---- row pass: reduce over this wave's 64 cols, rows of tileI ----
    #pragma unroll
    for (int mi = 0; mi < 4; mi++) {
        #pragma unroll
        for (int reg = 0; reg < 4; reg++) {
            const int rloc = wr * 64 + mi * 16 + quad * 4 + reg;
            const int lr   = rl[mi * 4 + reg];
            const int gi   = tileI + rloc;
            float pmin =  INFINITY;
            float nmax = -INFINITY;
            #pragma unroll
            for (int ni = 0; ni < 4; ni++) {
                const int gj  = tileJ + clocv[ni];
                const float g = acc[mi][ni][reg];
                const bool same = (lr == cl[ni]);
                if (same && gi != gj) pmin = fminf(pmin, g);
                if (!same)            nmax = fmaxf(nmax, g);
            }
            #pragma unroll
            for (int m = 1; m < 16; m <<= 1) {
                pmin = fminf(pmin, __shfl_xor(pmin, m));
                nmax = fmaxf(nmax, __shfl_xor(nmax, m));
            }
            if (l16 == 0) {
                if (pmin <  INFINITY) atomicMin(&posArr[gi], enc(pmin));
                if (nmax > -INFINITY) atomicMax(&negArr[gi], enc(nmax));
            }
        }
    }

    // ---- col pass (off-diag only): reduce over this wave's 64 rows ----
    if (!diag) {
        #pragma unroll
        for (int ni = 0; ni < 4; ni++) {
            const int lc = cl[ni];
            const int gj = tileJ + clocv[ni];
            float pmin =  INFINITY;
            float nmax = -INFINITY;
            #pragma unroll
            for (int mi = 0; mi < 4; mi++) {
                #pragma unroll
                for (int reg = 0; reg < 4; reg++) {
                    const float g = acc[mi][ni][reg];
                    const bool same = (rl[mi * 4 + reg] == lc);
                    if (same) pmin = fminf(pmin, g);
                    else      nmax = fmaxf(nmax, g);
                }
            }
            pmin = fminf(pmin, __shfl_xor(pmin, 16));
            pmin = fminf(pmin, __shfl_xor(pmin, 32));
            nmax = fmaxf(nmax, __shfl_xor(nmax, 16));
            nmax = fmaxf(nmax, __shfl_xor(nmax, 32));
            if (quad == 0) {
                if (pmin <  INFINITY) atomicMin(&posArr[gj], enc(pmin));
                if (nmax > -INFINITY) atomicMax(&negArr[gj], enc(nmax));
            }
        }
    }
}

// ---- kernel 3: per-row loss + mean over valid rows ----
__global__ void tl_final(const unsigned* __restrict__ posArr,
                         const unsigned* __restrict__ negArr,
                         float* __restrict__ out) {
    const int tid = threadIdx.x; // 1024 threads, 4 rows each, single pass
    uint4 pe4 = ((const uint4*)posArr)[tid];
    uint4 ne4 = ((const uint4*)negArr)[tid];
    unsigned pes[4] = {pe4.x, pe4.y, pe4.z, pe4.w};
    unsigned nes[4] = {ne4.x, ne4.y, ne4.z, ne4.w};
    float sum = 0.0f;
    int   count = 0;
    #pragma unroll
    for (int j = 0; j < 4; j++) {
        const bool valid = (pes[j] != POS_INIT) && (nes[j] != NEG_INIT);
        const float dap = sqrtf(fmaxf(2.0f - 2.0f * dec(pes[j]), 0.0f));
        const float dan = sqrtf(fmaxf(2.0f - 2.0f * dec(nes[j]), 0.0f));
        const float per = fmaxf(dap - dan + MARGIN, 0.0f);
        if (valid) { sum += per; count += 1; }
    }
    #pragma unroll
    for (int m = 32; m >= 1; m >>= 1) {
        sum   += __shfl_xor(sum, m);
        count += __shfl_xor(count, m);
    }
    __shared__ float ssum[16];
    __shared__ int   scnt[16];
    const int wave = tid >> 6, lane = tid & 63;
    if (lane == 0) { ssum[wave] = sum; scnt[wave] = count; }
    __syncthreads();
    if (tid == 0) {
        float s = 0.0f; int c = 0;
        #pragma unroll
        for (int w = 0; w < 16; w++) { s += ssum[w]; c += scnt[w]; }
        out[0] = (c > 0) ? (s / (float)c) : 0.0f;
    }
}

extern "C" void kernel_launch(void* const* d_in, const int* in_sizes, int n_in,
                              void* d_out, int out_size, void* d_ws, size_t ws_size,
                              hipStream_t stream) {
    const float* E      = (const float*)d_in[0];
    const int*   labels = (const int*)d_in[1];
    float*       out    = (float*)d_out;

    char* ws = (char*)d_ws;
    __hip_bfloat16* Ebf   = (__hip_bfloat16*)ws;                       // 4 MB
    unsigned* posArr      = (unsigned*)(ws + (size_t)NROW * DIM * 2);  // 16 KB
    unsigned* negArr      = posArr + NROW;                             // 16 KB

    tl_norm<<<NROW / 16, 256, 0, stream>>>(E, Ebf, posArr, negArr);
    tl_gram<<<NPAIR, 256, 0, stream>>>(Ebf, labels, posArr, negArr);
    tl_final<<<1, 1024, 0, stream>>>(posArr, negArr, out);
}